// Round 5
// baseline (260.521 us; speedup 1.0000x reference)
//
#include <hip/hip_runtime.h>

// Problem constants: N=32, C=3, H=W=512, SCALE=1 -> OUT=512, A=512,
// DENSE=4 -> thr0 = 4.0, ITERS=5.
#define NB   32
#define NC   3
#define HH   512
#define WW   512
#define AA   512
#define OUT  512

// ---------------- kernel 1: one wave64 per batch, barrier-free ------------
// Each lane owns 8 contiguous elements (e = lane*8 + j). All reductions and
// the inclusive scan are shfl-based; LDS is used only to hold the final
// cumsum for the binary search (single wave -> one cheap __syncthreads).
__global__ __launch_bounds__(64) void clip_cdf_wave(
    const float* __restrict__ attx, const float* __restrict__ atty,
    float* __restrict__ px, float* __restrict__ py)
{
    __shared__ float csx[AA], csy[AA];
    const int n    = blockIdx.x;
    const int lane = threadIdx.x;

    float ax[8], ay[8];
    {
        const float4* ap = (const float4*)(attx + n * AA);
        const float4* bp = (const float4*)(atty + n * AA);
        float4 a0 = ap[lane * 2], a1 = ap[lane * 2 + 1];
        float4 b0 = bp[lane * 2], b1 = bp[lane * 2 + 1];
        ax[0]=a0.x; ax[1]=a0.y; ax[2]=a0.z; ax[3]=a0.w;
        ax[4]=a1.x; ax[5]=a1.y; ax[6]=a1.z; ax[7]=a1.w;
        ay[0]=b0.x; ay[1]=b0.y; ay[2]=b0.z; ay[3]=b0.w;
        ay[4]=b1.x; ay[5]=b1.y; ay[6]=b1.z; ay[7]=b1.w;
    }

    // normalize * OUT
    float sx = 0.0f, sy = 0.0f;
#pragma unroll
    for (int j = 0; j < 8; ++j) { sx += ax[j]; sy += ay[j]; }
#pragma unroll
    for (int m = 32; m > 0; m >>= 1) {
        sx += __shfl_xor(sx, m, 64);
        sy += __shfl_xor(sy, m, 64);
    }
    const float scx = (float)OUT / sx;
    const float scy = (float)OUT / sy;
#pragma unroll
    for (int j = 0; j < 8; ++j) { ax[j] *= scx; ay[j] *= scy; }

    // 5 clip iterations, all in registers + shfl
#pragma unroll
    for (int it = 0; it < 5; ++it) {
        float mx = ax[0], my = ay[0];
#pragma unroll
        for (int j = 1; j < 8; ++j) { mx = fmaxf(mx, ax[j]); my = fmaxf(my, ay[j]); }
#pragma unroll
        for (int m = 32; m > 0; m >>= 1) {
            mx = fmaxf(mx, __shfl_xor(mx, m, 64));
            my = fmaxf(my, __shfl_xor(my, m, 64));
        }
        float tv = fminf(mx, my);
        if (it == 0) tv = fminf(tv, 4.0f);   // thr0 = DENSE*OUT/A
        float sax = 0.0f, say = 0.0f;
#pragma unroll
        for (int j = 0; j < 8; ++j) {
            ax[j] = fminf(ax[j], tv);  sax += ax[j];
            ay[j] = fminf(ay[j], tv);  say += ay[j];
        }
#pragma unroll
        for (int m = 32; m > 0; m >>= 1) {
            sax += __shfl_xor(sax, m, 64);
            say += __shfl_xor(say, m, 64);
        }
        const float dx = ((float)OUT - sax) * (1.0f / (float)AA);
        const float dy = ((float)OUT - say) * (1.0f / (float)AA);
#pragma unroll
        for (int j = 0; j < 8; ++j) { ax[j] += dx; ay[j] += dy; }
    }

    // dual inclusive scan: per-lane prefix + wave shfl scan of lane totals
    float psx[8], psy[8];
    float tx = 0.0f, ty = 0.0f;
#pragma unroll
    for (int j = 0; j < 8; ++j) {
        tx += ax[j]; psx[j] = tx;
        ty += ay[j]; psy[j] = ty;
    }
    float inx = tx, iny = ty;
#pragma unroll
    for (int off = 1; off < 64; off <<= 1) {
        float ux = __shfl_up(inx, off, 64);
        float uy = __shfl_up(iny, off, 64);
        if (lane >= off) { inx += ux; iny += uy; }
    }
    const float exx = inx - tx;   // exclusive prefix of this lane's chunk
    const float exy = iny - ty;
    const float totx = __shfl(inx, 63, 64);
    const float toty = __shfl(iny, 63, 64);

    ((float4*)csx)[lane * 2]     = make_float4(exx+psx[0], exx+psx[1], exx+psx[2], exx+psx[3]);
    ((float4*)csx)[lane * 2 + 1] = make_float4(exx+psx[4], exx+psx[5], exx+psx[6], exx+psx[7]);
    ((float4*)csy)[lane * 2]     = make_float4(exy+psy[0], exy+psy[1], exy+psy[2], exy+psy[3]);
    ((float4*)csy)[lane * 2 + 1] = make_float4(exy+psy[4], exy+psy[5], exy+psy[6], exy+psy[7]);
    __syncthreads();   // single wave: cheap; guarantees LDS visibility

    const float stx = totx * (1.0f / (float)OUT);
    const float sty = toty * (1.0f / (float)OUT);

    float outx[8], outy[8];
#pragma unroll
    for (int j = 0; j < 8; ++j) {
        const int t = lane * 8 + j;
        // x
        {
            const float tk = ((float)t + 0.5f) * stx;
            int lo = 0, hi = AA;
            while (lo < hi) {                       // proven-correct while form
                int mid = (lo + hi) >> 1;
                if (csx[mid] < tk) lo = mid + 1; else hi = mid;
            }
            int jj = min(lo, AA - 1);
            float cprev = (jj > 0) ? csx[jj - 1] : 0.0f;
            float dens  = csx[jj] - cprev;
            float p     = (float)jj + (tk - cprev) / fmaxf(dens, 1e-6f);
            outx[j] = 2.0f * p * (1.0f / (float)AA) - 1.0f;
        }
        // y
        {
            const float tk = ((float)t + 0.5f) * sty;
            int lo = 0, hi = AA;
            while (lo < hi) {
                int mid = (lo + hi) >> 1;
                if (csy[mid] < tk) lo = mid + 1; else hi = mid;
            }
            int jj = min(lo, AA - 1);
            float cprev = (jj > 0) ? csy[jj - 1] : 0.0f;
            float dens  = csy[jj] - cprev;
            float p     = (float)jj + (tk - cprev) / fmaxf(dens, 1e-6f);
            outy[j] = 2.0f * p * (1.0f / (float)AA) - 1.0f;
        }
    }
    ((float4*)(px + n * OUT))[lane * 2]     = make_float4(outx[0], outx[1], outx[2], outx[3]);
    ((float4*)(px + n * OUT))[lane * 2 + 1] = make_float4(outx[4], outx[5], outx[6], outx[7]);
    ((float4*)(py + n * OUT))[lane * 2]     = make_float4(outy[0], outy[1], outy[2], outy[3]);
    ((float4*)(py + n * OUT))[lane * 2 + 1] = make_float4(outy[4], outy[5], outy[6], outy[7]);
}

// ---------------- kernel 2: grid build + bilinear sample -------------------
// 384 threads: thread = (channel c = tid>>7, float4 pixel-group g = tid&127).
// One float4 sampled store per thread; grid written as float4 by tid<256.
// 6 input rows staged in LDS with coalesced float4 loads (2 rounds).
__global__ __launch_bounds__(384) void sample_kernel(
    const float* __restrict__ data, const float* __restrict__ px,
    const float* __restrict__ py, float* __restrict__ sampled,
    float2* __restrict__ grid)
{
    __shared__ float lrow[6][WW];   // 12 KB

    const int d = blockIdx.x;
    const int g = ((d & 7) << 11) + (d >> 3);   // XCD swizzle (bijection)
    const int n = g >> 9;
    const int i = g & (OUT - 1);

    const float gy  = py[n * OUT + i];
    const float iy  = (gy + 1.0f) * 0.5f * (float)(HH - 1);
    const float y0f = floorf(iy);
    const float wy  = iy - y0f;
    int y0 = (int)y0f;
    y0 = max(0, min(y0, HH - 1));
    const int y1 = min(y0 + 1, HH - 1);

    const float* dbase = data + (size_t)n * NC * HH * WW;
    const int tid = threadIdx.x;

    // stage 6 rows: 768 float4s over 384 threads (2 each), coalesced
#pragma unroll
    for (int k = 0; k < 2; ++k) {
        const int idx = tid + k * 384;           // 0..767
        const int row = idx >> 7;                // 0..5 (128 float4 per row)
        const int q   = idx & 127;
        const int c   = (row < 3) ? row : row - 3;
        const int y   = (row < 3) ? y0 : y1;
        ((float4*)&lrow[row][0])[q] =
            ((const float4*)(dbase + ((size_t)c * HH + y) * WW))[q];
    }
    __syncthreads();

    const int   c  = tid >> 7;          // channel 0..2
    const int   gq = tid & 127;         // pixel group (4 px)
    const float4 pv = ((const float4*)(px + n * OUT))[gq];
    const float pxv[4] = { pv.x, pv.y, pv.z, pv.w };

    const float* r0 = &lrow[c][0];
    const float* r1 = &lrow[3 + c][0];

    float res[4];
#pragma unroll
    for (int u = 0; u < 4; ++u) {
        const float ix  = (pxv[u] + 1.0f) * 0.5f * (float)(WW - 1);
        const float x0f = floorf(ix);
        const float wx  = ix - x0f;
        int x0 = (int)x0f; x0 = max(0, min(x0, WW - 1));
        const int x1 = min(x0 + 1, WW - 1);
        const float a0 = r0[x0], a1 = r0[x1];
        const float b0 = r1[x0], b1 = r1[x1];
        const float top = a0 + wx * (a1 - a0);
        const float bot = b0 + wx * (b1 - b0);
        res[u] = top + wy * (bot - top);
    }
    float* sbase = sampled + (size_t)n * NC * HH * WW
                 + (size_t)c * HH * WW + (size_t)i * WW;
    ((float4*)sbase)[gq] = make_float4(res[0], res[1], res[2], res[3]);

    if (tid < 256) {
        const float2 p2 = ((const float2*)(px + n * OUT))[tid];
        float4* gb = (float4*)(grid + ((size_t)n * OUT + i) * OUT);
        gb[tid] = make_float4(p2.x, gy, p2.y, gy);
    }
}

extern "C" void kernel_launch(void* const* d_in, const int* in_sizes, int n_in,
                              void* d_out, int out_size, void* d_ws, size_t ws_size,
                              hipStream_t stream) {
    const float* data = (const float*)d_in[0];
    const float* attx = (const float*)d_in[1];
    const float* atty = (const float*)d_in[2];

    float* px = (float*)d_ws;                 // NB*OUT floats
    float* py = px + NB * OUT;                // NB*OUT floats

    float*  out     = (float*)d_out;
    float*  sampled = out;                                        // (N,C,H,W)
    float2* grid    = (float2*)(out + (size_t)NB * NC * HH * WW); // (N,H,W,2)

    clip_cdf_wave<<<NB, 64, 0, stream>>>(attx, atty, px, py);
    sample_kernel<<<NB * OUT, 384, 0, stream>>>(data, px, py, sampled, grid);
}